// Round 1
// baseline (431.784 us; speedup 1.0000x reference)
//
#include <hip/hip_runtime.h>

#define IC   32     // in_chunks
#define NE   64     // num_experts
#define D    128    // expert_size
#define IF   4096   // in_features
#define OF   8192   // out_features
#define TB   128    // batch rows per block

__global__ __launch_bounds__(256, 1)
void trident_moe_kernel(const float* __restrict__ x,
                        const float* __restrict__ routing,
                        const float* __restrict__ We,
                        const float* __restrict__ noise,
                        float* __restrict__ out) {
    // LDS: transposed+swizzled We[e] (j-major) and x_routed tile (j-major)
    __shared__ float sWe[D * D];   // 64 KB
    __shared__ float sXr[TB * D];  // 64 KB
    __shared__ float s_sign[IC];
    __shared__ int   s_chunk[IC];
    __shared__ float s_csign[IC];
    __shared__ int   s_cnt;

    const int t  = threadIdx.x;
    const int e  = blockIdx.y;   // expert
    const int bt = blockIdx.x;   // batch tile

    // ---- ternarize this expert's routing column (exact: mul then add, no fma) ----
    if (t < IC) {
        float w  = routing[t * NE + e];
        float nz = noise[t * NE + e];
        float wn = __fadd_rn(w, __fmul_rn(0.1f, nz));
        s_sign[t] = (wn < -0.5f) ? -1.0f : ((wn > 0.5f) ? 1.0f : 0.0f);
    }
    __syncthreads();
    if (t == 0) {
        int c = 0;
        for (int i = 0; i < IC; ++i) {
            float s = s_sign[i];
            if (s != 0.0f) { s_chunk[c] = i; s_csign[c] = s; ++c; }
        }
        s_cnt = c;
    }
    __syncthreads();
    const int nnz = s_cnt;

    const int c4 = t & 31;   // float4 lane within a 128-float row
    const int r0 = t >> 5;   // 0..7

    float4* out4 = (float4*)out;
    const size_t orow4 = OF / 4;  // 2048

    if (nnz == 0) {
        // inactive expert: coalesced zero-fill of our output tile
        const float4 z = make_float4(0.f, 0.f, 0.f, 0.f);
        #pragma unroll
        for (int p = 0; p < TB / 8; ++p) {
            size_t row = (size_t)(bt * TB + p * 8 + r0);
            out4[row * orow4 + e * (D / 4) + c4] = z;
        }
        return;
    }

    // ---- stage We[e] transposed: (r,j) -> sWe[j*128 + ((r>>3)^((j>>2)&15))*8 + (r&7)] ----
    const float4* We4 = (const float4*)(We + (size_t)e * D * D);
    #pragma unroll
    for (int p = 0; p < D / 8; ++p) {
        int r = p * 8 + r0;
        float4 w4 = We4[r * (D / 4) + c4];
        float wv[4] = {w4.x, w4.y, w4.z, w4.w};
        #pragma unroll
        for (int k = 0; k < 4; ++k) {
            int j = c4 * 4 + k;
            int blk = (r >> 3) ^ ((j >> 2) & 15);
            sWe[j * D + blk * 8 + (r & 7)] = wv[k];
        }
    }

    // ---- compute x_routed tile and stage transposed+swizzled ----
    const float4* x4p = (const float4*)x;
    const size_t xrow4 = IF / 4;  // 1024
    #pragma unroll
    for (int p = 0; p < TB / 8; ++p) {
        int b = p * 8 + r0;
        size_t row = (size_t)(bt * TB + b);
        float4 acc = make_float4(0.f, 0.f, 0.f, 0.f);
        for (int m = 0; m < nnz; ++m) {
            int   i = s_chunk[m];
            float s = s_csign[m];
            float4 v = x4p[row * xrow4 + i * (D / 4) + c4];
            acc.x += s * v.x; acc.y += s * v.y;
            acc.z += s * v.z; acc.w += s * v.w;
        }
        float av[4] = {acc.x, acc.y, acc.z, acc.w};
        #pragma unroll
        for (int k = 0; k < 4; ++k) {
            int j = c4 * 4 + k;
            int blk = (b >> 3) ^ ((j >> 2) & 15);
            sXr[j * TB + blk * 8 + (b & 7)] = av[k];
        }
    }
    __syncthreads();

    // ---- register-tiled fp32 GEMM: out[b][r] = sum_j WeT[j][r] * XrT[j][b] ----
    const int rg = t & 15;   // r-block 0..15 (8 r's each)
    const int bg = t >> 4;   // b-block 0..15 (8 b's each)
    float acc[8][8];
    #pragma unroll
    for (int a = 0; a < 8; ++a)
        #pragma unroll
        for (int c = 0; c < 8; ++c) acc[a][c] = 0.f;

    #pragma unroll 2
    for (int j = 0; j < D; ++j) {
        const int sw = (j >> 2) & 15;
        const float4* wr = (const float4*)&sWe[j * D  + ((rg ^ sw) << 3)];
        const float4* xr = (const float4*)&sXr[j * TB + ((bg ^ sw) << 3)];
        float4 w0 = wr[0], w1 = wr[1];
        float4 x0 = xr[0], x1 = xr[1];
        float wv[8] = {w0.x, w0.y, w0.z, w0.w, w1.x, w1.y, w1.z, w1.w};
        float xv[8] = {x0.x, x0.y, x0.z, x0.w, x1.x, x1.y, x1.z, x1.w};
        #pragma unroll
        for (int a = 0; a < 8; ++a)
            #pragma unroll
            for (int c = 0; c < 8; ++c)
                acc[a][c] += wv[a] * xv[c];
    }

    // ---- epilogue: rows bt*TB + bg*8 + c, cols e*128 + rg*8 + {0..7} ----
    #pragma unroll
    for (int c = 0; c < 8; ++c) {
        size_t row  = (size_t)(bt * TB + bg * 8 + c);
        size_t base = row * orow4 + e * (D / 4) + rg * 2;
        out4[base]     = make_float4(acc[0][c], acc[1][c], acc[2][c], acc[3][c]);
        out4[base + 1] = make_float4(acc[4][c], acc[5][c], acc[6][c], acc[7][c]);
    }
}

extern "C" void kernel_launch(void* const* d_in, const int* in_sizes, int n_in,
                              void* d_out, int out_size, void* d_ws, size_t ws_size,
                              hipStream_t stream) {
    const float* x       = (const float*)d_in[0];
    const float* routing = (const float*)d_in[1];
    const float* We      = (const float*)d_in[2];
    const float* noise   = (const float*)d_in[3];
    float* out = (float*)d_out;

    int B = in_sizes[0] / IF;           // 8192
    dim3 grid(B / TB, NE);              // (64, 64)
    trident_moe_kernel<<<grid, 256, 0, stream>>>(x, routing, We, noise, out);
}